// Round 7
// baseline (248.237 us; speedup 1.0000x reference)
//
#include <hip/hip_runtime.h>

// out[b,c] = logsumexp_d(x[b,d] + log_softmax(weight)[c,d])
//          = log( sum_d exp(x[b,d]) * softmax(weight)[c,d] )
// x:[8192,2048] f32, weight:[10,2048] f32
constexpr int B = 8192;
constexpr int D = 2048;   // P*N = 64*32
constexpr int C = 10;

// ---------------- Kernel 1: p[c,:] = softmax(weight[c,:]) ----------------
__global__ __launch_bounds__(256) void softmax_w_kernel(
    const float* __restrict__ w, float* __restrict__ p) {
  const int c = blockIdx.x;
  const int t = threadIdx.x;          // 0..255
  const int lane = t & 63, wid = t >> 6;

  const float4* wr = reinterpret_cast<const float4*>(w + c * D);
  float4 v0 = wr[t];          // d = 4t .. 4t+3
  float4 v1 = wr[t + 256];    // d = 1024 + 4t ..

  // block max
  float m = fmaxf(fmaxf(fmaxf(v0.x, v0.y), fmaxf(v0.z, v0.w)),
                  fmaxf(fmaxf(v1.x, v1.y), fmaxf(v1.z, v1.w)));
#pragma unroll
  for (int o = 1; o < 64; o <<= 1) m = fmaxf(m, __shfl_xor(m, o));
  __shared__ float sred[4];
  if (lane == 0) sred[wid] = m;
  __syncthreads();
  m = fmaxf(fmaxf(sred[0], sred[1]), fmaxf(sred[2], sred[3]));
  __syncthreads();  // sred reused below

  float4 e0, e1;
  e0.x = __expf(v0.x - m); e0.y = __expf(v0.y - m);
  e0.z = __expf(v0.z - m); e0.w = __expf(v0.w - m);
  e1.x = __expf(v1.x - m); e1.y = __expf(v1.y - m);
  e1.z = __expf(v1.z - m); e1.w = __expf(v1.w - m);

  float s = (e0.x + e0.y + e0.z + e0.w) + (e1.x + e1.y + e1.z + e1.w);
#pragma unroll
  for (int o = 1; o < 64; o <<= 1) s += __shfl_xor(s, o);
  if (lane == 0) sred[wid] = s;
  __syncthreads();
  s = (sred[0] + sred[1]) + (sred[2] + sred[3]);

  const float inv = 1.0f / s;
  float4 q0 = {e0.x * inv, e0.y * inv, e0.z * inv, e0.w * inv};
  float4 q1 = {e1.x * inv, e1.y * inv, e1.z * inv, e1.w * inv};
  float4* pr = reinterpret_cast<float4*>(p + c * D);
  pr[t] = q0;
  pr[t + 256] = q1;
}

// ---------------- Kernel 2: out[b,c] = log( exp(x[b,:]) . p[c,:] ) ----------------
// Block = 256 threads = 4 waves; each wave handles R=2 consecutive rows.
// grid = B/8 = 1024 blocks -> 4096 waves (16/CU from grid).
// __launch_bounds__(256,4): 4 waves/SIMD minimum -> VGPR <= 128, stops the
// unroll register bloat that gave 240 VGPRs / 9% occupancy last round.
__global__ __launch_bounds__(256, 4) void lse_main_kernel(
    const float* __restrict__ x, const float* __restrict__ p,
    float* __restrict__ out) {
  const int t = threadIdx.x;
  const int lane = t & 63, wid = t >> 6;
  const int row0 = blockIdx.x * 8 + wid * 2;   // 2 rows per wave

  const float4* xr = reinterpret_cast<const float4*>(x + (size_t)row0 * D);
  const float4* p4 = reinterpret_cast<const float4*>(p);
  constexpr int D4 = D / 4;  // 512

  float acc0[C], acc1[C];
#pragma unroll
  for (int c = 0; c < C; ++c) { acc0[c] = 0.0f; acc1[c] = 0.0f; }

#pragma unroll
  for (int j = 0; j < 8; ++j) {
    const int f4 = j * 64 + lane;

    float4 xv0 = xr[f4];
    float4 xv1 = xr[D4 + f4];

    float4 e0, e1;
    e0.x = __expf(xv0.x); e0.y = __expf(xv0.y);
    e0.z = __expf(xv0.z); e0.w = __expf(xv0.w);
    e1.x = __expf(xv1.x); e1.y = __expf(xv1.y);
    e1.z = __expf(xv1.z); e1.w = __expf(xv1.w);

#pragma unroll
    for (int c = 0; c < C; ++c) {
      const float4 pv = p4[c * D4 + f4];
      acc0[c] += e0.x * pv.x + e0.y * pv.y + e0.z * pv.z + e0.w * pv.w;
      acc1[c] += e1.x * pv.x + e1.y * pv.y + e1.z * pv.z + e1.w * pv.w;
    }
  }

  // wave butterfly reduction + store (precise logf in epilogue — cost is nil)
#pragma unroll
  for (int c = 0; c < C; ++c) {
    float v0 = acc0[c], v1 = acc1[c];
#pragma unroll
    for (int o = 1; o < 64; o <<= 1) {
      v0 += __shfl_xor(v0, o);
      v1 += __shfl_xor(v1, o);
    }
    if (lane == c) {
      out[(size_t)row0 * C + c] = logf(v0);
      out[(size_t)(row0 + 1) * C + c] = logf(v1);
    }
  }
}

extern "C" void kernel_launch(void* const* d_in, const int* in_sizes, int n_in,
                              void* d_out, int out_size, void* d_ws, size_t ws_size,
                              hipStream_t stream) {
  const float* x = (const float*)d_in[0];       // [B, D]
  const float* w = (const float*)d_in[1];       // [C, D]
  float* out = (float*)d_out;                   // [B, C]
  float* p = (float*)d_ws;                      // [C, D] scratch (80 KB)

  softmax_w_kernel<<<C, 256, 0, stream>>>(w, p);
  lse_main_kernel<<<B / 8, 256, 0, stream>>>(x, p, out);
}

// Round 8
// 106.166 us; speedup vs baseline: 2.3382x; 2.3382x over previous
//
#include <hip/hip_runtime.h>

// out[b,c] = logsumexp_d(x[b,d] + log_softmax(weight)[c,d])
//          = log( sum_d exp(x[b,d]) * softmax(weight)[c,d] )
// x:[8192,2048] f32, weight:[10,2048] f32
constexpr int B = 8192;
constexpr int D = 2048;   // P*N = 64*32
constexpr int C = 10;

// ---------------- Kernel 1: p[c,:] = softmax(weight[c,:]) ----------------
__global__ __launch_bounds__(256) void softmax_w_kernel(
    const float* __restrict__ w, float* __restrict__ p) {
  const int c = blockIdx.x;
  const int t = threadIdx.x;          // 0..255
  const int lane = t & 63, wid = t >> 6;

  const float4* wr = reinterpret_cast<const float4*>(w + c * D);
  float4 v0 = wr[t];          // d = 4t .. 4t+3
  float4 v1 = wr[t + 256];    // d = 1024 + 4t ..

  // block max
  float m = fmaxf(fmaxf(fmaxf(v0.x, v0.y), fmaxf(v0.z, v0.w)),
                  fmaxf(fmaxf(v1.x, v1.y), fmaxf(v1.z, v1.w)));
#pragma unroll
  for (int o = 1; o < 64; o <<= 1) m = fmaxf(m, __shfl_xor(m, o));
  __shared__ float sred[4];
  if (lane == 0) sred[wid] = m;
  __syncthreads();
  m = fmaxf(fmaxf(sred[0], sred[1]), fmaxf(sred[2], sred[3]));
  __syncthreads();  // sred reused below

  float4 e0, e1;
  e0.x = __expf(v0.x - m); e0.y = __expf(v0.y - m);
  e0.z = __expf(v0.z - m); e0.w = __expf(v0.w - m);
  e1.x = __expf(v1.x - m); e1.y = __expf(v1.y - m);
  e1.z = __expf(v1.z - m); e1.w = __expf(v1.w - m);

  float s = (e0.x + e0.y + e0.z + e0.w) + (e1.x + e1.y + e1.z + e1.w);
#pragma unroll
  for (int o = 1; o < 64; o <<= 1) s += __shfl_xor(s, o);
  if (lane == 0) sred[wid] = s;
  __syncthreads();
  s = (sred[0] + sred[1]) + (sred[2] + sred[3]);

  const float inv = 1.0f / s;
  float4 q0 = {e0.x * inv, e0.y * inv, e0.z * inv, e0.w * inv};
  float4 q1 = {e1.x * inv, e1.y * inv, e1.z * inv, e1.w * inv};
  float4* pr = reinterpret_cast<float4*>(p + c * D);
  pr[t] = q0;
  pr[t + 256] = q1;
}

// ---------------- Kernel 2: out[b,c] = log( exp(x[b,:]) . p[c,:] ) ----------------
// 4 waves/block, R=2 rows per wave, grid = B/8 = 1024 blocks (16 waves/CU).
// j-loop is ROLLED (#pragma unroll 1): R7 showed full unroll + reg cap =>
// scratch spill (263 MB writes). Live set ~96 regs fits the 128-cap of
// __launch_bounds__(256,4) without spilling. Branchless one-ahead x prefetch
// ((j+1)&7 wraps to cached line on last iter, stays in-bounds).
__global__ __launch_bounds__(256, 4) void lse_main_kernel(
    const float* __restrict__ x, const float* __restrict__ p,
    float* __restrict__ out) {
  const int t = threadIdx.x;
  const int lane = t & 63, wid = t >> 6;
  const int row0 = blockIdx.x * 8 + wid * 2;   // 2 rows per wave

  const float4* xr = reinterpret_cast<const float4*>(x + (size_t)row0 * D);
  const float4* p4 = reinterpret_cast<const float4*>(p);
  constexpr int D4 = D / 4;  // 512

  float acc0[C], acc1[C];
#pragma unroll
  for (int c = 0; c < C; ++c) { acc0[c] = 0.0f; acc1[c] = 0.0f; }

  float4 nx0 = xr[lane];
  float4 nx1 = xr[D4 + lane];

#pragma unroll 1
  for (int j = 0; j < 8; ++j) {
    const float4 cx0 = nx0, cx1 = nx1;
    const int fn = ((j + 1) & 7) * 64 + lane;   // next-iter prefetch index
    nx0 = xr[fn];
    nx1 = xr[D4 + fn];

    float4 e0, e1;
    e0.x = __expf(cx0.x); e0.y = __expf(cx0.y);
    e0.z = __expf(cx0.z); e0.w = __expf(cx0.w);
    e1.x = __expf(cx1.x); e1.y = __expf(cx1.y);
    e1.z = __expf(cx1.z); e1.w = __expf(cx1.w);

    const int f4 = j * 64 + lane;
#pragma unroll
    for (int c = 0; c < C; ++c) {
      const float4 pv = p4[c * D4 + f4];
      acc0[c] += e0.x * pv.x + e0.y * pv.y + e0.z * pv.z + e0.w * pv.w;
      acc1[c] += e1.x * pv.x + e1.y * pv.y + e1.z * pv.z + e1.w * pv.w;
    }
  }

  // wave butterfly reduction + store (precise logf in epilogue — cost is nil)
#pragma unroll
  for (int c = 0; c < C; ++c) {
    float v0 = acc0[c], v1 = acc1[c];
#pragma unroll
    for (int o = 1; o < 64; o <<= 1) {
      v0 += __shfl_xor(v0, o);
      v1 += __shfl_xor(v1, o);
    }
    if (lane == c) {
      out[(size_t)row0 * C + c] = logf(v0);
      out[(size_t)(row0 + 1) * C + c] = logf(v1);
    }
  }
}

extern "C" void kernel_launch(void* const* d_in, const int* in_sizes, int n_in,
                              void* d_out, int out_size, void* d_ws, size_t ws_size,
                              hipStream_t stream) {
  const float* x = (const float*)d_in[0];       // [B, D]
  const float* w = (const float*)d_in[1];       // [C, D]
  float* out = (float*)d_out;                   // [B, C]
  float* p = (float*)d_ws;                      // [C, D] scratch (80 KB)

  softmax_w_kernel<<<C, 256, 0, stream>>>(w, p);
  lse_main_kernel<<<B / 8, 256, 0, stream>>>(x, p, out);
}

// Round 9
// 100.797 us; speedup vs baseline: 2.4627x; 1.0533x over previous
//
#include <hip/hip_runtime.h>

// out[b,c] = logsumexp_d(x[b,d] + log_softmax(weight)[c,d])
//          = log( sum_d exp(x[b,d]) * softmax(weight)[c,d] )
// x:[8192,2048] f32, weight:[10,2048] f32
constexpr int B = 8192;
constexpr int D = 2048;   // P*N = 64*32
constexpr int C = 10;
constexpr int D4 = D / 4; // 512 float4 per row

// ---------------- Kernel 1: p[c,:] = softmax(weight[c,:]) ----------------
__global__ __launch_bounds__(256) void softmax_w_kernel(
    const float* __restrict__ w, float* __restrict__ p) {
  const int c = blockIdx.x;
  const int t = threadIdx.x;          // 0..255
  const int lane = t & 63, wid = t >> 6;

  const float4* wr = reinterpret_cast<const float4*>(w + c * D);
  float4 v0 = wr[t];          // d = 4t .. 4t+3
  float4 v1 = wr[t + 256];    // d = 1024 + 4t ..

  float m = fmaxf(fmaxf(fmaxf(v0.x, v0.y), fmaxf(v0.z, v0.w)),
                  fmaxf(fmaxf(v1.x, v1.y), fmaxf(v1.z, v1.w)));
#pragma unroll
  for (int o = 1; o < 64; o <<= 1) m = fmaxf(m, __shfl_xor(m, o));
  __shared__ float sred[4];
  if (lane == 0) sred[wid] = m;
  __syncthreads();
  m = fmaxf(fmaxf(sred[0], sred[1]), fmaxf(sred[2], sred[3]));
  __syncthreads();  // sred reused below

  float4 e0, e1;
  e0.x = __expf(v0.x - m); e0.y = __expf(v0.y - m);
  e0.z = __expf(v0.z - m); e0.w = __expf(v0.w - m);
  e1.x = __expf(v1.x - m); e1.y = __expf(v1.y - m);
  e1.z = __expf(v1.z - m); e1.w = __expf(v1.w - m);

  float s = (e0.x + e0.y + e0.z + e0.w) + (e1.x + e1.y + e1.z + e1.w);
#pragma unroll
  for (int o = 1; o < 64; o <<= 1) s += __shfl_xor(s, o);
  if (lane == 0) sred[wid] = s;
  __syncthreads();
  s = (sred[0] + sred[1]) + (sred[2] + sred[3]);

  const float inv = 1.0f / s;
  float4 q0 = {e0.x * inv, e0.y * inv, e0.z * inv, e0.w * inv};
  float4 q1 = {e1.x * inv, e1.y * inv, e1.z * inv, e1.w * inv};
  float4* pr = reinterpret_cast<float4*>(p + c * D);
  pr[t] = q0;
  pr[t + 256] = q1;
}

// ---------------- Kernel 2: out[b,c] = log( exp(x[b,:]) . p[c,:] ) ----------------
// 512 threads = 8 waves/block, R=2 rows per wave -> 16 rows/block.
// grid = B/16 = 512 blocks; 80 KB LDS/block -> 2 blocks/CU (160 KB pool),
// 16 waves/CU. p staged in LDS once per block: kills the 335 MB of L2
// p-re-reads that co-limited R8 (~22 TB/s demand vs 34.5 ceiling).
// Inner p-reads: contiguous ds_read_b128, conflict-free.
__global__ __launch_bounds__(512, 2) void lse_main_kernel(
    const float* __restrict__ x, const float* __restrict__ p,
    float* __restrict__ out) {
  __shared__ float4 plds[C * D4];   // 10 * 512 * 16B = 80 KB

  const int t = threadIdx.x;        // 0..511
  const int lane = t & 63, wid = t >> 6;

  // one-time stage p -> LDS (coalesced, 10 float4 per thread)
#pragma unroll
  for (int k = 0; k < C * D4 / 512; ++k)
    plds[k * 512 + t] = reinterpret_cast<const float4*>(p)[k * 512 + t];
  __syncthreads();

  const int row0 = blockIdx.x * 16 + wid * 2;   // 2 rows per wave
  const float4* xr = reinterpret_cast<const float4*>(x + (size_t)row0 * D);

  float acc0[C], acc1[C];
#pragma unroll
  for (int c = 0; c < C; ++c) { acc0[c] = 0.0f; acc1[c] = 0.0f; }

  float4 nx0 = xr[lane];
  float4 nx1 = xr[D4 + lane];

#pragma unroll 1
  for (int j = 0; j < 8; ++j) {
    const float4 cx0 = nx0, cx1 = nx1;
    const int fn = ((j + 1) & 7) * 64 + lane;   // next-iter prefetch (wraps, in-bounds)
    nx0 = xr[fn];
    nx1 = xr[D4 + fn];

    float4 e0, e1;
    e0.x = __expf(cx0.x); e0.y = __expf(cx0.y);
    e0.z = __expf(cx0.z); e0.w = __expf(cx0.w);
    e1.x = __expf(cx1.x); e1.y = __expf(cx1.y);
    e1.z = __expf(cx1.z); e1.w = __expf(cx1.w);

    const int f4 = j * 64 + lane;
#pragma unroll
    for (int c = 0; c < C; ++c) {
      const float4 pv = plds[c * D4 + f4];
      acc0[c] += e0.x * pv.x + e0.y * pv.y + e0.z * pv.z + e0.w * pv.w;
      acc1[c] += e1.x * pv.x + e1.y * pv.y + e1.z * pv.z + e1.w * pv.w;
    }
  }

  // wave butterfly reduction + store
#pragma unroll
  for (int c = 0; c < C; ++c) {
    float v0 = acc0[c], v1 = acc1[c];
#pragma unroll
    for (int o = 1; o < 64; o <<= 1) {
      v0 += __shfl_xor(v0, o);
      v1 += __shfl_xor(v1, o);
    }
    if (lane == c) {
      out[(size_t)row0 * C + c] = logf(v0);
      out[(size_t)(row0 + 1) * C + c] = logf(v1);
    }
  }
}

extern "C" void kernel_launch(void* const* d_in, const int* in_sizes, int n_in,
                              void* d_out, int out_size, void* d_ws, size_t ws_size,
                              hipStream_t stream) {
  const float* x = (const float*)d_in[0];       // [B, D]
  const float* w = (const float*)d_in[1];       // [C, D]
  float* out = (float*)d_out;                   // [B, C]
  float* p = (float*)d_ws;                      // [C, D] scratch (80 KB)

  softmax_w_kernel<<<C, 256, 0, stream>>>(w, p);
  lse_main_kernel<<<B / 16, 512, 0, stream>>>(x, p, out);
}

// Round 12
// 100.778 us; speedup vs baseline: 2.4632x; 1.0002x over previous
//
#include <hip/hip_runtime.h>

// out[b,c] = logsumexp_d(x[b,d] + log_softmax(weight)[c,d])
//          = log( sum_d exp(x[b,d]) * softmax(weight)[c,d] )
// x:[8192,2048] f32, weight:[10,2048] f32
constexpr int B = 8192;
constexpr int D = 2048;   // P*N = 64*32
constexpr int C = 10;
constexpr int D4 = D / 4; // 512 float4 per row

// ---------------- Kernel 1: p[c,:] = softmax(weight[c,:]) ----------------
__global__ __launch_bounds__(256) void softmax_w_kernel(
    const float* __restrict__ w, float* __restrict__ p) {
  const int c = blockIdx.x;
  const int t = threadIdx.x;          // 0..255
  const int lane = t & 63, wid = t >> 6;

  const float4* wr = reinterpret_cast<const float4*>(w + c * D);
  float4 v0 = wr[t];          // d = 4t .. 4t+3
  float4 v1 = wr[t + 256];    // d = 1024 + 4t ..

  float m = fmaxf(fmaxf(fmaxf(v0.x, v0.y), fmaxf(v0.z, v0.w)),
                  fmaxf(fmaxf(v1.x, v1.y), fmaxf(v1.z, v1.w)));
#pragma unroll
  for (int o = 1; o < 64; o <<= 1) m = fmaxf(m, __shfl_xor(m, o));
  __shared__ float sred[4];
  if (lane == 0) sred[wid] = m;
  __syncthreads();
  m = fmaxf(fmaxf(sred[0], sred[1]), fmaxf(sred[2], sred[3]));
  __syncthreads();  // sred reused below

  float4 e0, e1;
  e0.x = __expf(v0.x - m); e0.y = __expf(v0.y - m);
  e0.z = __expf(v0.z - m); e0.w = __expf(v0.w - m);
  e1.x = __expf(v1.x - m); e1.y = __expf(v1.y - m);
  e1.z = __expf(v1.z - m); e1.w = __expf(v1.w - m);

  float s = (e0.x + e0.y + e0.z + e0.w) + (e1.x + e1.y + e1.z + e1.w);
#pragma unroll
  for (int o = 1; o < 64; o <<= 1) s += __shfl_xor(s, o);
  if (lane == 0) sred[wid] = s;
  __syncthreads();
  s = (sred[0] + sred[1]) + (sred[2] + sred[3]);

  const float inv = 1.0f / s;
  float4 q0 = {e0.x * inv, e0.y * inv, e0.z * inv, e0.w * inv};
  float4 q1 = {e1.x * inv, e1.y * inv, e1.z * inv, e1.w * inv};
  float4* pr = reinterpret_cast<float4*>(p + c * D);
  pr[t] = q0;
  pr[t + 256] = q1;
}

// ---------------- Kernel 2: out[b,c] = log( exp(x[b,:]) . p[c,:] ) ----------------
// 512 threads = 8 waves/block, R=2 rows/wave, grid = B/16 = 512 blocks.
// 80 KB LDS/block -> 2 blocks/CU (LDS-capped), 16 waves/CU.
// Change vs R9: x prefetch depth 1 -> 2. Issue-to-use distance ~600+ cyc
// covers the ~900-cyc HBM latency with 4 resident waves/SIMD (R9's
// distance-1 left ~600-cyc stalls per iteration). +16 VGPR, well under the
// 256-reg cap of (512,2); occupancy is LDS-capped so regs are free.
__global__ __launch_bounds__(512, 2) void lse_main_kernel(
    const float* __restrict__ x, const float* __restrict__ p,
    float* __restrict__ out) {
  __shared__ float4 plds[C * D4];   // 10 * 512 * 16B = 80 KB

  const int t = threadIdx.x;        // 0..511
  const int lane = t & 63, wid = t >> 6;

  // one-time stage p -> LDS (coalesced, 10 float4 per thread)
#pragma unroll
  for (int k = 0; k < C * D4 / 512; ++k)
    plds[k * 512 + t] = reinterpret_cast<const float4*>(p)[k * 512 + t];
  __syncthreads();

  const int row0 = blockIdx.x * 16 + wid * 2;   // 2 rows per wave
  const float4* xr = reinterpret_cast<const float4*>(x + (size_t)row0 * D);

  float acc0[C], acc1[C];
#pragma unroll
  for (int c = 0; c < C; ++c) { acc0[c] = 0.0f; acc1[c] = 0.0f; }

  // prefetch pipeline, depth 2
  float4 a0 = xr[lane],      a1 = xr[D4 + lane];        // j = 0
  float4 b0 = xr[64 + lane], b1 = xr[D4 + 64 + lane];   // j = 1

#pragma unroll 1
  for (int j = 0; j < 8; ++j) {
    const float4 cx0 = a0, cx1 = a1;
    a0 = b0; a1 = b1;
    const int fn = ((j + 2) & 7) * 64 + lane;   // j+2 prefetch (wraps, in-bounds)
    b0 = xr[fn];
    b1 = xr[D4 + fn];

    float4 e0, e1;
    e0.x = __expf(cx0.x); e0.y = __expf(cx0.y);
    e0.z = __expf(cx0.z); e0.w = __expf(cx0.w);
    e1.x = __expf(cx1.x); e1.y = __expf(cx1.y);
    e1.z = __expf(cx1.z); e1.w = __expf(cx1.w);

    const int f4 = j * 64 + lane;
#pragma unroll
    for (int c = 0; c < C; ++c) {
      const float4 pv = plds[c * D4 + f4];
      acc0[c] += e0.x * pv.x + e0.y * pv.y + e0.z * pv.z + e0.w * pv.w;
      acc1[c] += e1.x * pv.x + e1.y * pv.y + e1.z * pv.z + e1.w * pv.w;
    }
  }

  // wave butterfly reduction + store
#pragma unroll
  for (int c = 0; c < C; ++c) {
    float v0 = acc0[c], v1 = acc1[c];
#pragma unroll
    for (int o = 1; o < 64; o <<= 1) {
      v0 += __shfl_xor(v0, o);
      v1 += __shfl_xor(v1, o);
    }
    if (lane == c) {
      out[(size_t)row0 * C + c] = logf(v0);
      out[(size_t)(row0 + 1) * C + c] = logf(v1);
    }
  }
}

extern "C" void kernel_launch(void* const* d_in, const int* in_sizes, int n_in,
                              void* d_out, int out_size, void* d_ws, size_t ws_size,
                              hipStream_t stream) {
  const float* x = (const float*)d_in[0];       // [B, D]
  const float* w = (const float*)d_in[1];       // [C, D]
  float* out = (float*)d_out;                   // [B, C]
  float* p = (float*)d_ws;                      // [C, D] scratch (80 KB)

  softmax_w_kernel<<<C, 256, 0, stream>>>(w, p);
  lse_main_kernel<<<B / 16, 512, 0, stream>>>(x, p, out);
}